// Round 4
// baseline (165.971 us; speedup 1.0000x reference)
//
#include <hip/hip_runtime.h>
#include <cstddef>

// B=16, h=8, Ch=32, H=W=56, N=3136
//   heads 0-1 -> 3x3 (w3,b3), cbase hh*32
//   heads 2-4 -> 5x5 (w5,b5), cbase hh*32-64
//   heads 5-7 -> 7x7 (w7,b7), cbase hh*32-160
// out[b][n][hh*32+ch] = q[b][hh][n][ch] * dwconv(v)[b][hh][n][ch]
//
// R9: multi-row-per-lane. R5/R6/R8 all pinned at ~53us across occupancies
// 8-16 waves/CU and 1-2.5x VMEM redundancy => time tracks total LDS+VMEM
// issue volume. Each lane now owns R=3..4 consecutive output rows, so each
// staged input row is ds_read ONCE and feeds R outputs: conv reads drop
// K*NR -> (1+2P/R)*NR per row (~2.4x), staging writes/loads 17.5 -> 10 per
// row. Block = 14 output rows (waves x {4,3,3,4}), stages 14+2P rows once
// (149 KB LDS, 1 block/CU -- R6 proved occupancy isn't the lever).
// Out stores are NONTEMPORAL: the 51 MB write stream stops evicting q/v
// from L3 (FETCH_SIZE attributes this independently).
// LDS row layout as R8: stride 58 px, lead pad 3, 2-px zero gaps = x-pads
// (full for K<=5; K=7 outer +-3 px via mL/mR lane masks, proven R8).

#define BH 16
#define NH 8
#define CH 32
#define HW 56
#define NN (HW*HW)
#define ROWB (HW*CH*4)          // 7168 B per image row
#define RS 58                   // LDS row stride in px (56 + 2 gap)
#define NROWS_MAX 20            // 14 + 2*3 (K=7)
#define BUF_PX (3 + NROWS_MAX*RS + 1)   // 1164 px
#define BUF_FLOATS (BUF_PX*CH)  // 37248 floats = 148992 B

typedef float f32x4 __attribute__((ext_vector_type(4)));
typedef unsigned int u32x4 __attribute__((ext_vector_type(4)));

__device__ __forceinline__ f32x4 bload(__amdgpu_buffer_rsrc_t rs, int voff) {
    u32x4 u = __builtin_amdgcn_raw_buffer_load_b128(rs, voff, 0, 0);
    f32x4 f; __builtin_memcpy(&f, &u, 16); return f;
}

// One wave computes R consecutive output rows (y0+sw .. y0+sw+R-1).
// Input staged rows s = sw+rr, rr in [0, R+2P): read window ONCE, apply to
// every output row t with dy = rr - t in [0,K).
template<int K, int R>
__device__ __forceinline__ void conv_rows(
    const float* __restrict__ q, float* __restrict__ out,
    const float* __restrict__ bias,
    int b, int hh, int y0, int sw, int cbase,
    const float* __restrict__ w_lds, const float* __restrict__ bufs,
    int lane)
{
    constexpr int P  = K / 2;
    constexpr int NR = 7 + K - 1;       // window px per 7-px strip
    const int xseg = lane >> 3;         // 8 x-strips of 7 px
    const int chq  = lane & 7;          // 8 ch-quads
    const int x0   = xseg * 7;
    const int ch   = chq * 4;

    // K=7 edge masks: window px -3/+58 land on neighbor-row data (not gap).
    const float mL = (xseg == 0) ? 0.f : 1.f;
    const float mR = (xseg == 7) ? 0.f : 1.f;

    const f32x4 bias4 = *(const f32x4*)(bias + cbase + ch);
    f32x4 acc[R][7];
#pragma unroll
    for (int u = 0; u < R; ++u)
#pragma unroll
        for (int i = 0; i < 7; ++i) acc[u][i] = bias4;

    // rr loop kept RUNTIME (not unrolled): bounds icache (~5 KB body/K),
    // guards below are wave-uniform scalar branches.
    for (int rr = 0; rr < R + 2 * P; ++rr) {
        const float* rb = bufs + (size_t)((3 - P + x0) + (sw + rr) * RS) * CH + ch;
        f32x4 r[NR];
#pragma unroll
        for (int j = 0; j < NR; ++j)
            r[j] = *(const f32x4*)(rb + j * CH);
        if constexpr (K == 7) { r[0] *= mL; r[NR - 1] *= mR; }

#pragma unroll
        for (int u = 0; u < R; ++u) {
            const int dy = rr - u;
            if ((unsigned)dy < (unsigned)K) {
#pragma unroll
                for (int dx = 0; dx < K; ++dx) {
                    const f32x4 w4 = *(const f32x4*)(w_lds + (dy * K + dx) * CH + ch);
#pragma unroll
                    for (int i = 0; i < 7; ++i)
                        acc[u][i] += r[i + dx] * w4;
                }
            }
        }
    }

    // Epilogue per row: q load (L3-cached), multiply, NONTEMPORAL store.
    const size_t plane = ((size_t)b * NH + hh) * (size_t)NN * CH;
#pragma unroll
    for (int u = 0; u < R; ++u) {
        const int y = y0 + sw + u;
        const float* qrow = q + plane + (size_t)y * (HW * CH);
        float* obase = out + ((size_t)b * NN + (size_t)y * HW) * (NH * CH) + hh * CH + ch;
#pragma unroll
        for (int i = 0; i < 7; ++i) {
            const int px = x0 + i;
            const f32x4 q4 = *(const f32x4*)(qrow + (size_t)px * CH + ch);
            const f32x4 o  = acc[u][i] * q4;
            __builtin_nontemporal_store(o, (f32x4*)(obase + (size_t)px * (NH * CH)));
        }
    }
}

template<int K>
__device__ __forceinline__ void run_head(
    const float* __restrict__ q, const float* __restrict__ v,
    const float* __restrict__ w, const float* __restrict__ bias,
    float* __restrict__ out, int b, int hh, int y0, int cbase,
    float* __restrict__ w_lds, float* __restrict__ bufs)
{
    constexpr int P = K / 2;
    constexpr int NROWS = 14 + 2 * P;   // staged rows per block
    constexpr int NS = (NROWS + 3) / 4; // staged rows per wave (max)
    const int t = threadIdx.x;

    // Stage weights into LDS, layout [tap][c].
    const int nw = K * K * CH;
    for (int i = t; i < nw; i += 256) {
        int tap = i >> 5, c = i & 31;
        w_lds[tap * CH + c] = w[(cbase + c) * (K * K) + tap];
    }

    // Zero pad px: lead 3, 2-px gap after each row, 1 trailing.
    {
        f32x4 z = {0.f, 0.f, 0.f, 0.f};
        const int NG = 3 + 2 * NROWS + 1;
        for (int i = t; i < NG * 8; i += 256) {
            const int g = i >> 3, sub = i & 7;
            int px;
            if (g < 3) px = g;
            else if (g < 3 + 2 * NROWS) {
                const int s = (g - 3) >> 1;
                px = 3 + s * RS + 56 + ((g - 3) & 1);
            } else px = 3 + NROWS * RS;
            *(f32x4*)(bufs + (size_t)px * CH + sub * 4) = z;
        }
    }

    const int wid  = t >> 6;
    const int lane = t & 63;
    const size_t plane = ((size_t)b * NH + hh) * (size_t)NN * CH;
    const float* vb = v + plane;

    // Cooperative staging: wave wid stages rows wid, wid+4, ... All loads
    // issued first (ld[] fully register-resident, static indexing), then
    // ds_writes -- maximizes VMEM overlap within the single wave/SIMD.
    // OOB rows: num_records=0 -> zeros = y zero-padding (proven R2-R4).
    f32x4 ld[NS][7];
#pragma unroll
    for (int n = 0; n < NS; ++n) {
        const int s = wid + n * 4;
        if (s < NROWS) {
            const int gy = y0 - P + s;
            const bool ok = (unsigned)gy < (unsigned)HW;
            __amdgpu_buffer_rsrc_t rs = __builtin_amdgcn_make_buffer_rsrc(
                (void*)(vb + (ptrdiff_t)gy * (HW * CH)), (short)0, ok ? ROWB : 0, 0x00020000);
#pragma unroll
            for (int k = 0; k < 7; ++k) ld[n][k] = bload(rs, k * 1024 + lane * 16);
        }
    }
#pragma unroll
    for (int n = 0; n < NS; ++n) {
        const int s = wid + n * 4;
        if (s < NROWS) {
            float* dst = bufs + (size_t)(3 + s * RS) * CH;
#pragma unroll
            for (int k = 0; k < 7; ++k)
                *(f32x4*)(dst + k * 256 + lane * 4) = ld[n][k];
        }
    }
    __syncthreads();                    // only barrier in the kernel

    // Row split {4,3,3,4} over 14 rows; waves exit independently after.
    if      (wid == 0) conv_rows<K, 4>(q, out, bias, b, hh, y0, 0,  cbase, w_lds, bufs, lane);
    else if (wid == 1) conv_rows<K, 3>(q, out, bias, b, hh, y0, 4,  cbase, w_lds, bufs, lane);
    else if (wid == 2) conv_rows<K, 3>(q, out, bias, b, hh, y0, 7,  cbase, w_lds, bufs, lane);
    else               conv_rows<K, 4>(q, out, bias, b, hh, y0, 10, cbase, w_lds, bufs, lane);
}

__global__ __launch_bounds__(256, 1)   // 155.3 KB LDS -> 1 block/CU
void clusterformer_fused(const float* __restrict__ q, const float* __restrict__ v,
                         const float* __restrict__ w3, const float* __restrict__ b3,
                         const float* __restrict__ w5, const float* __restrict__ b5,
                         const float* __restrict__ w7, const float* __restrict__ b7,
                         float* __restrict__ out)
{
    __shared__ __align__(16) float bufs[BUF_FLOATS];   // 148992 B
    __shared__ __align__(16) float w_lds[49 * CH];     // 6272 B

    // bid -> (plane p, ygroup): XCD-local planes, heavy heads (K7) first.
    const int bid  = blockIdx.x;
    const int p_lo = bid & 7;
    const int t2   = bid >> 3;         // 0..63
    const int p_hi = t2 >> 2;          // 0..15
    const int yg   = t2 & 3;           // 0..3
    const int p    = p_hi * 8 + p_lo;  // 0..127
    const int b    = p & 15;
    const int hhp  = p >> 4;           // dispatch-ordered head
    const int hh   = (hhp < 3) ? (5 + hhp) : ((hhp < 6) ? (hhp - 1) : (hhp - 6));
    const int y0   = yg * 14;

    if (hh < 2)      run_head<3>(q, v, w3, b3, out, b, hh, y0, hh * 32,       w_lds, bufs);
    else if (hh < 5) run_head<5>(q, v, w5, b5, out, b, hh, y0, hh * 32 - 64,  w_lds, bufs);
    else             run_head<7>(q, v, w7, b7, out, b, hh, y0, hh * 32 - 160, w_lds, bufs);
}

extern "C" void kernel_launch(void* const* d_in, const int* in_sizes, int n_in,
                              void* d_out, int out_size, void* d_ws, size_t ws_size,
                              hipStream_t stream) {
    const float* q  = (const float*)d_in[0];
    const float* v  = (const float*)d_in[1];
    const float* w3 = (const float*)d_in[2];
    const float* b3 = (const float*)d_in[3];
    const float* w5 = (const float*)d_in[4];
    const float* b5 = (const float*)d_in[5];
    const float* w7 = (const float*)d_in[6];
    const float* b7 = (const float*)d_in[7];
    float* out = (float*)d_out;

    const int grid = BH * NH * 4;      // 512 blocks of 256 threads
    clusterformer_fused<<<grid, 256, 0, stream>>>(q, v, w3, b3, w5, b5, w7, b7, out);
}

// Round 5
// 161.751 us; speedup vs baseline: 1.0261x; 1.0261x over previous
//
#include <hip/hip_runtime.h>
#include <cstddef>

// B=16, h=8, Ch=32, H=W=56, N=3136
//   heads 0-1 -> 3x3 (w3,b3), cbase hh*32
//   heads 2-4 -> 5x5 (w5,b5), cbase hh*32-64
//   heads 5-7 -> 7x7 (w7,b7), cbase hh*32-160
// out[b][n][hh*32+ch] = q[b][hh][n][ch] * dwconv(v)[b][hh][n][ch]
//
// R10: write-locality scheduling. R5/6/8/9 are all pinned at ~53us with
// IDENTICAL hbm_bytes ~104MB => effective 2.0 TB/s: DRAM-pattern-bound.
// Out is [b][n][256ch]; each head-block writes a 128B slice per 1-KB px
// record (128B/1KB stride => ~1-2 line-writes per DRAM page activation,
// ~18% write efficiency). Fix: all 8 heads of a (b, y-slab) now occupy
// CONSECUTIVE scheduling slots on the SAME XCD (bid = slot*8 + xcd, head
// fastest within slot) => their 128-B lines of the same records co-reside
// in the 4MB L2 (4 slabs x 784KB = 3.1MB dirty) and evict as COMPLETE
// 1-KB records -> ~8x DRAM page locality on the write stream. nt-store
// reverted (bypassing L2 defeats exactly this coalescing).
// Compute structure = R9 (lowest issue volume): lane owns 3-4 output rows,
// block stages 14+2P rows once (149KB LDS, 1 block/CU).

#define BH 16
#define NH 8
#define CH 32
#define HW 56
#define NN (HW*HW)
#define ROWB (HW*CH*4)          // 7168 B per image row
#define RS 58                   // LDS row stride in px (56 + 2 gap)
#define NROWS_MAX 20            // 14 + 2*3 (K=7)
#define BUF_PX (3 + NROWS_MAX*RS + 1)   // 1164 px
#define BUF_FLOATS (BUF_PX*CH)  // 37248 floats = 148992 B

typedef float f32x4 __attribute__((ext_vector_type(4)));
typedef unsigned int u32x4 __attribute__((ext_vector_type(4)));

__device__ __forceinline__ f32x4 bload(__amdgpu_buffer_rsrc_t rs, int voff) {
    u32x4 u = __builtin_amdgcn_raw_buffer_load_b128(rs, voff, 0, 0);
    f32x4 f; __builtin_memcpy(&f, &u, 16); return f;
}

// One wave computes R consecutive output rows (y0+sw .. y0+sw+R-1).
// Input staged rows s = sw+rr, rr in [0, R+2P): read window ONCE, apply to
// every output row u with dy = rr - u in [0,K).
template<int K, int R>
__device__ __forceinline__ void conv_rows(
    const float* __restrict__ q, float* __restrict__ out,
    const float* __restrict__ bias,
    int b, int hh, int y0, int sw, int cbase,
    const float* __restrict__ w_lds, const float* __restrict__ bufs,
    int lane)
{
    constexpr int P  = K / 2;
    constexpr int NR = 7 + K - 1;       // window px per 7-px strip
    const int xseg = lane >> 3;         // 8 x-strips of 7 px
    const int chq  = lane & 7;          // 8 ch-quads
    const int x0   = xseg * 7;
    const int ch   = chq * 4;

    // K=7 edge masks: window px -3/+58 land on neighbor-row data (not gap).
    const float mL = (xseg == 0) ? 0.f : 1.f;
    const float mR = (xseg == 7) ? 0.f : 1.f;

    const f32x4 bias4 = *(const f32x4*)(bias + cbase + ch);
    f32x4 acc[R][7];
#pragma unroll
    for (int u = 0; u < R; ++u)
#pragma unroll
        for (int i = 0; i < 7; ++i) acc[u][i] = bias4;

    // rr loop kept RUNTIME (not unrolled): bounds icache, guards below are
    // wave-uniform scalar branches.
    for (int rr = 0; rr < R + 2 * P; ++rr) {
        const float* rb = bufs + (size_t)((3 - P + x0) + (sw + rr) * RS) * CH + ch;
        f32x4 r[NR];
#pragma unroll
        for (int j = 0; j < NR; ++j)
            r[j] = *(const f32x4*)(rb + j * CH);
        if constexpr (K == 7) { r[0] *= mL; r[NR - 1] *= mR; }

#pragma unroll
        for (int u = 0; u < R; ++u) {
            const int dy = rr - u;
            if ((unsigned)dy < (unsigned)K) {
#pragma unroll
                for (int dx = 0; dx < K; ++dx) {
                    const f32x4 w4 = *(const f32x4*)(w_lds + (dy * K + dx) * CH + ch);
#pragma unroll
                    for (int i = 0; i < 7; ++i)
                        acc[u][i] += r[i + dx] * w4;
                }
            }
        }
    }

    // Epilogue per row: q load, multiply, PLAIN store (dirty lines must
    // linger in L2 so the 8 concurrent heads assemble full 1-KB records).
    const size_t plane = ((size_t)b * NH + hh) * (size_t)NN * CH;
#pragma unroll
    for (int u = 0; u < R; ++u) {
        const int y = y0 + sw + u;
        const float* qrow = q + plane + (size_t)y * (HW * CH);
        float* obase = out + ((size_t)b * NN + (size_t)y * HW) * (NH * CH) + hh * CH + ch;
#pragma unroll
        for (int i = 0; i < 7; ++i) {
            const int px = x0 + i;
            const f32x4 q4 = *(const f32x4*)(qrow + (size_t)px * CH + ch);
            *(f32x4*)(obase + (size_t)px * (NH * CH)) = acc[u][i] * q4;
        }
    }
}

template<int K>
__device__ __forceinline__ void run_head(
    const float* __restrict__ q, const float* __restrict__ v,
    const float* __restrict__ w, const float* __restrict__ bias,
    float* __restrict__ out, int b, int hh, int y0, int cbase,
    float* __restrict__ w_lds, float* __restrict__ bufs)
{
    constexpr int P = K / 2;
    constexpr int NROWS = 14 + 2 * P;   // staged rows per block
    constexpr int NS = (NROWS + 3) / 4; // staged rows per wave (max)
    const int t = threadIdx.x;

    // Stage weights into LDS, layout [tap][c].
    const int nw = K * K * CH;
    for (int i = t; i < nw; i += 256) {
        int tap = i >> 5, c = i & 31;
        w_lds[tap * CH + c] = w[(cbase + c) * (K * K) + tap];
    }

    // Zero pad px: lead 3, 2-px gap after each row, 1 trailing.
    {
        f32x4 z = {0.f, 0.f, 0.f, 0.f};
        const int NG = 3 + 2 * NROWS + 1;
        for (int i = t; i < NG * 8; i += 256) {
            const int g = i >> 3, sub = i & 7;
            int px;
            if (g < 3) px = g;
            else if (g < 3 + 2 * NROWS) {
                const int s = (g - 3) >> 1;
                px = 3 + s * RS + 56 + ((g - 3) & 1);
            } else px = 3 + NROWS * RS;
            *(f32x4*)(bufs + (size_t)px * CH + sub * 4) = z;
        }
    }

    const int wid  = t >> 6;
    const int lane = t & 63;
    const size_t plane = ((size_t)b * NH + hh) * (size_t)NN * CH;
    const float* vb = v + plane;

    // Cooperative staging: wave wid stages rows wid, wid+4, ... All loads
    // issued first (ld[] register-resident, static indexing), then writes.
    // OOB rows: num_records=0 -> zeros = y zero-padding (proven R2-R4).
    f32x4 ld[NS][7];
#pragma unroll
    for (int n = 0; n < NS; ++n) {
        const int s = wid + n * 4;
        if (s < NROWS) {
            const int gy = y0 - P + s;
            const bool ok = (unsigned)gy < (unsigned)HW;
            __amdgpu_buffer_rsrc_t rs = __builtin_amdgcn_make_buffer_rsrc(
                (void*)(vb + (ptrdiff_t)gy * (HW * CH)), (short)0, ok ? ROWB : 0, 0x00020000);
#pragma unroll
            for (int k = 0; k < 7; ++k) ld[n][k] = bload(rs, k * 1024 + lane * 16);
        }
    }
#pragma unroll
    for (int n = 0; n < NS; ++n) {
        const int s = wid + n * 4;
        if (s < NROWS) {
            float* dst = bufs + (size_t)(3 + s * RS) * CH;
#pragma unroll
            for (int k = 0; k < 7; ++k)
                *(f32x4*)(dst + k * 256 + lane * 4) = ld[n][k];
        }
    }
    __syncthreads();                    // only barrier in the kernel

    // Row split {4,3,3,4} over 14 rows; waves exit independently after.
    if      (wid == 0) conv_rows<K, 4>(q, out, bias, b, hh, y0, 0,  cbase, w_lds, bufs, lane);
    else if (wid == 1) conv_rows<K, 3>(q, out, bias, b, hh, y0, 4,  cbase, w_lds, bufs, lane);
    else if (wid == 2) conv_rows<K, 3>(q, out, bias, b, hh, y0, 7,  cbase, w_lds, bufs, lane);
    else               conv_rows<K, 4>(q, out, bias, b, hh, y0, 10, cbase, w_lds, bufs, lane);
}

__global__ __launch_bounds__(256, 1)   // 155.3 KB LDS -> 1 block/CU
void clusterformer_fused(const float* __restrict__ q, const float* __restrict__ v,
                         const float* __restrict__ w3, const float* __restrict__ b3,
                         const float* __restrict__ w5, const float* __restrict__ b5,
                         const float* __restrict__ w7, const float* __restrict__ b7,
                         float* __restrict__ out)
{
    __shared__ __align__(16) float bufs[BUF_FLOATS];   // 148992 B
    __shared__ __align__(16) float w_lds[49 * CH];     // 6272 B

    // bid -> (xcd, slot): slot enumerates (yg, b_hi, head) with HEAD the
    // fastest-varying field. All 8 head-blocks of one (b, y-slab) occupy 8
    // consecutive slots on ONE XCD -> run concurrently, assemble complete
    // out records in that XCD's L2. b&7 == xcd keeps q/v planes XCD-local.
    const int bid  = blockIdx.x;
    const int xcd  = bid & 7;
    const int slot = bid >> 3;         // 0..63 within XCD
    const int hhp  = slot & 7;         // head, fastest
    const int t2   = slot >> 3;        // 0..7
    const int b    = ((t2 & 1) << 3) | xcd;
    const int yg   = t2 >> 1;          // 0..3
    const int hh   = (hhp < 3) ? (5 + hhp) : ((hhp < 6) ? (hhp - 1) : (hhp - 6));
    const int y0   = yg * 14;

    if (hh < 2)      run_head<3>(q, v, w3, b3, out, b, hh, y0, hh * 32,       w_lds, bufs);
    else if (hh < 5) run_head<5>(q, v, w5, b5, out, b, hh, y0, hh * 32 - 64,  w_lds, bufs);
    else             run_head<7>(q, v, w7, b7, out, b, hh, y0, hh * 32 - 160, w_lds, bufs);
}

extern "C" void kernel_launch(void* const* d_in, const int* in_sizes, int n_in,
                              void* d_out, int out_size, void* d_ws, size_t ws_size,
                              hipStream_t stream) {
    const float* q  = (const float*)d_in[0];
    const float* v  = (const float*)d_in[1];
    const float* w3 = (const float*)d_in[2];
    const float* b3 = (const float*)d_in[3];
    const float* w5 = (const float*)d_in[4];
    const float* b5 = (const float*)d_in[5];
    const float* w7 = (const float*)d_in[6];
    const float* b7 = (const float*)d_in[7];
    float* out = (float*)d_out;

    const int grid = BH * NH * 4;      // 512 blocks of 256 threads
    clusterformer_fused<<<grid, 256, 0, stream>>>(q, v, w3, b3, w5, b5, w7, b7, out);
}